// Round 1
// baseline (739.764 us; speedup 1.0000x reference)
//
#include <hip/hip_runtime.h>
#include <stdint.h>

// NeuralSDE: y_{t+1} = y_t + f(y_t)*dt + g(y_t)*(sqrt(dt)*n_t)
// f,g: Linear(32->128) -> ReLU -> Linear(128->32), B=4096, T=500.
// Strategy: 256 blocks x 512 threads; block owns 16 batch rows for all T steps.
// 8 waves = {drift,diff} x {4 hidden chunks of 32}. bf16 MFMA 16x16x32,
// fp32 state held in registers (1 element per thread).

#define BATCH   4096
#define DIM     32
#define HID     128
#define STEP_E  (BATCH * DIM)   // 131072 elements per time slice

typedef float f32x4  __attribute__((ext_vector_type(4)));
typedef short bf16x8 __attribute__((ext_vector_type(8)));

__device__ __forceinline__ short f2bf(float f) {
    union { float f; uint32_t u; } v; v.f = f;
    uint32_t u = v.u;
    u += 0x7fffu + ((u >> 16) & 1u);   // RNE
    return (short)(u >> 16);
}
__device__ __forceinline__ uint32_t pack2(float a, float b) {
    return (uint32_t)(uint16_t)f2bf(a) | ((uint32_t)(uint16_t)f2bf(b) << 16);
}

__global__ __launch_bounds__(512, 1) void sde_kernel(
    const float* __restrict__ y0,
    const float* __restrict__ noise,
    const float* __restrict__ dw1, const float* __restrict__ db1,
    const float* __restrict__ dw2, const float* __restrict__ db2,
    const float* __restrict__ gw1, const float* __restrict__ gb1,
    const float* __restrict__ gw2, const float* __restrict__ gb2,
    float* __restrict__ out, int T)
{
    // LDS. Strides padded to kill bank conflicts while keeping 16B alignment.
    __shared__ __align__(16) short Ybf[16 * 32];        // state tile, bf16 [b][d]
    __shared__ __align__(16) short Hbuf[8][16 * 40];    // per-wave h, [b][32+pad]
    __shared__ __align__(16) float Fpart[8][16 * 36];   // partial f^T, [b][32+pad]

    const int tid  = threadIdx.x;
    const int w    = tid >> 6;          // wave 0..7
    const int lane = tid & 63;
    const int q    = lane >> 4;         // quad 0..3
    const int bb   = lane & 15;         // batch-within-tile for matrix ops
    const int mlp  = w >> 2;            // 0 = drift, 1 = diffusion
    const int hs   = w & 3;             // hidden chunk [32*hs, 32*hs+32)
    const int r0   = blockIdx.x * 16;   // first batch row of this tile

    const float* w1p = mlp ? gw1 : dw1;
    const float* b1p = mlp ? gb1 : db1;
    const float* w2p = mlp ? gw2 : dw2;

    // ---- preload weight A-fragments (A[m=lane&15][k=q*8+j]) ----
    bf16x8 a1[2], a2[2];
    float bias1[2][4];
    for (int hc = 0; hc < 2; ++hc) {
        const int hrow = 32 * hs + 16 * hc + bb;        // W1 row = hidden idx
        const float* p = w1p + hrow * DIM + 8 * q;
        bf16x8 tmp;
        #pragma unroll
        for (int j = 0; j < 8; ++j) tmp[j] = f2bf(p[j]);
        a1[hc] = tmp;
        #pragma unroll
        for (int r = 0; r < 4; ++r)
            bias1[hc][r] = b1p[32 * hs + 16 * hc + 4 * q + r];
    }
    for (int nc = 0; nc < 2; ++nc) {
        const int orow = 16 * nc + bb;                  // W2 row = out idx
        const float* p = w2p + orow * HID + 32 * hs + 8 * q;
        bf16x8 tmp;
        #pragma unroll
        for (int j = 0; j < 8; ++j) tmp[j] = f2bf(p[j]);
        a2[nc] = tmp;
    }

    // ---- update-thread identity: one state element per thread ----
    const int ub = tid >> 5;            // batch row within tile 0..15
    const int ud = tid & 31;            // state dim 0..31
    const float b2d = db2[ud];
    const float b2g = gb2[ud];
    const size_t base = (size_t)(r0 + ub) * DIM + ud;

    float y_reg = y0[base];
    out[base]   = y_reg;                // out[0] = y0
    Ybf[ub * 32 + ud] = f2bf(y_reg);

    float n_use = noise[base];
    float n_mid = (T > 1) ? noise[(size_t)STEP_E + base] : 0.0f;
    __syncthreads();

    const float dt = 0.01f, sdt = 0.1f;
    const f32x4 z = {0.f, 0.f, 0.f, 0.f};

    for (int t = 0; t < T; ++t) {
        // prefetch noise[t+2] (clamped) — ~2 steps of latency hiding
        int tn = t + 2; if (tn > T - 1) tn = T - 1;
        const float n_far = noise[(size_t)tn * STEP_E + base];

        // ===== phase A: matrix work =====
        // y fragment doubles as B operand of h^T = W1 * y^T (n=lane&15, k=q*8+j)
        const bf16x8 by = *(const bf16x8*)(&Ybf[bb * 32 + 8 * q]);

        f32x4 hh[2];
        hh[0] = __builtin_amdgcn_mfma_f32_16x16x32_bf16(a1[0], by, z, 0, 0, 0);
        hh[1] = __builtin_amdgcn_mfma_f32_16x16x32_bf16(a1[1], by, z, 0, 0, 0);

        // bias + ReLU + bf16 pack, C-layout -> LDS [batch][hidden_local]
        #pragma unroll
        for (int hc = 0; hc < 2; ++hc) {
            const float v0 = fmaxf(hh[hc][0] + bias1[hc][0], 0.f);
            const float v1 = fmaxf(hh[hc][1] + bias1[hc][1], 0.f);
            const float v2 = fmaxf(hh[hc][2] + bias1[hc][2], 0.f);
            const float v3 = fmaxf(hh[hc][3] + bias1[hc][3], 0.f);
            uint2 dw; dw.x = pack2(v0, v1); dw.y = pack2(v2, v3);
            *(uint2*)(&Hbuf[w][bb * 40 + 16 * hc + 4 * q]) = dw;
        }

        // read back as B operand of f^T = W2 * h^T (k local = q*8+j)
        const bf16x8 hf = *(const bf16x8*)(&Hbuf[w][bb * 40 + 8 * q]);

        const f32x4 p0 = __builtin_amdgcn_mfma_f32_16x16x32_bf16(a2[0], hf, z, 0, 0, 0);
        const f32x4 p1 = __builtin_amdgcn_mfma_f32_16x16x32_bf16(a2[1], hf, z, 0, 0, 0);
        *(f32x4*)(&Fpart[w][bb * 36 + 0  + 4 * q]) = p0;   // out dims 0..15
        *(f32x4*)(&Fpart[w][bb * 36 + 16 + 4 * q]) = p1;   // out dims 16..31
        __syncthreads();

        // ===== phase B: Euler–Maruyama update (1 element / thread) =====
        const int fo = ub * 36 + ud;
        const float fsum = Fpart[0][fo] + Fpart[1][fo] + Fpart[2][fo] + Fpart[3][fo];
        const float gsum = Fpart[4][fo] + Fpart[5][fo] + Fpart[6][fo] + Fpart[7][fo];

        const float y1 = y_reg + (fsum + b2d) * dt + (gsum + b2g) * (sdt * n_use);
        y_reg = y1;
        out[(size_t)(t + 1) * STEP_E + base] = y1;   // coalesced 2KB/block
        Ybf[ub * 32 + ud] = f2bf(y1);

        n_use = n_mid; n_mid = n_far;
        __syncthreads();
    }
}

extern "C" void kernel_launch(void* const* d_in, const int* in_sizes, int n_in,
                              void* d_out, int out_size, void* d_ws, size_t ws_size,
                              hipStream_t stream) {
    // inputs: 0 ts, 1 y0, 2 noise, 3..6 drift w1/b1/w2/b2, 7..10 diff w1/b1/w2/b2
    const float* y0    = (const float*)d_in[1];
    const float* noise = (const float*)d_in[2];
    const float* dw1   = (const float*)d_in[3];
    const float* db1   = (const float*)d_in[4];
    const float* dw2   = (const float*)d_in[5];
    const float* db2   = (const float*)d_in[6];
    const float* gw1   = (const float*)d_in[7];
    const float* gb1   = (const float*)d_in[8];
    const float* gw2   = (const float*)d_in[9];
    const float* gb2   = (const float*)d_in[10];
    float* out = (float*)d_out;

    const int T = in_sizes[2] / STEP_E;   // 500

    sde_kernel<<<BATCH / 16, 512, 0, stream>>>(
        y0, noise, dw1, db1, dw2, db2, gw1, gb1, gw2, gb2, out, T);
}

// Round 2
// 678.687 us; speedup vs baseline: 1.0900x; 1.0900x over previous
//
#include <hip/hip_runtime.h>
#include <stdint.h>

// NeuralSDE: y_{t+1} = y_t + f(y_t)*dt + g(y_t)*(sqrt(dt)*n_t)
// f,g: Linear(32->128) -> ReLU -> Linear(128->32), B=4096, T=500.
// 256 blocks x 512 threads; block owns 16 batch rows for all T steps.
// 8 waves = {drift,diff} x {4 hidden chunks of 32}. bf16 MFMA 16x16x32,
// fp32 state in registers (1 element per thread).
//
// R2 change: __syncthreads() drains vmcnt(0) -> forced noise-load + store-ack
// completion every step (latency-bound, ~2090 cyc/step). Replace with raw
// "s_waitcnt lgkmcnt(0); s_barrier" so global memory ops stay in flight
// across barriers; deepen noise prefetch to 4 steps.

#define BATCH   4096
#define DIM     32
#define HID     128
#define STEP_E  (BATCH * DIM)   // 131072 elements per time slice

// LDS-only barrier: drain LDS writes (cross-wave visibility) but leave
// global loads/stores (vmcnt) in flight. Single asm block so no memory op
// can be scheduled between the waitcnt and the barrier.
#define LDS_BARRIER() asm volatile("s_waitcnt lgkmcnt(0)\n\ts_barrier" ::: "memory")

typedef float f32x4  __attribute__((ext_vector_type(4)));
typedef short bf16x8 __attribute__((ext_vector_type(8)));

__device__ __forceinline__ short f2bf(float f) {
    union { float f; uint32_t u; } v; v.f = f;
    uint32_t u = v.u;
    u += 0x7fffu + ((u >> 16) & 1u);   // RNE
    return (short)(u >> 16);
}
__device__ __forceinline__ uint32_t pack2(float a, float b) {
    return (uint32_t)(uint16_t)f2bf(a) | ((uint32_t)(uint16_t)f2bf(b) << 16);
}

__global__ __launch_bounds__(512, 1) void sde_kernel(
    const float* __restrict__ y0,
    const float* __restrict__ noise,
    const float* __restrict__ dw1, const float* __restrict__ db1,
    const float* __restrict__ dw2, const float* __restrict__ db2,
    const float* __restrict__ gw1, const float* __restrict__ gb1,
    const float* __restrict__ gw2, const float* __restrict__ gb2,
    float* __restrict__ out, int T)
{
    __shared__ __align__(16) short Ybf[16 * 32];        // state tile, bf16 [b][d]
    __shared__ __align__(16) short Hbuf[8][16 * 40];    // per-wave h, [b][32+pad]
    __shared__ __align__(16) float Fpart[8][16 * 36];   // partial f^T, [b][32+pad]

    const int tid  = threadIdx.x;
    const int w    = tid >> 6;          // wave 0..7
    const int lane = tid & 63;
    const int q    = lane >> 4;         // quad 0..3
    const int bb   = lane & 15;         // batch-within-tile for matrix ops
    const int mlp  = w >> 2;            // 0 = drift, 1 = diffusion
    const int hs   = w & 3;             // hidden chunk [32*hs, 32*hs+32)
    const int r0   = blockIdx.x * 16;   // first batch row of this tile

    const float* w1p = mlp ? gw1 : dw1;
    const float* b1p = mlp ? gb1 : db1;
    const float* w2p = mlp ? gw2 : dw2;

    // ---- preload weight A-fragments (A[m=lane&15][k=q*8+j]) ----
    bf16x8 a1[2], a2[2];
    float bias1[2][4];
    for (int hc = 0; hc < 2; ++hc) {
        const int hrow = 32 * hs + 16 * hc + bb;        // W1 row = hidden idx
        const float* p = w1p + hrow * DIM + 8 * q;
        bf16x8 tmp;
        #pragma unroll
        for (int j = 0; j < 8; ++j) tmp[j] = f2bf(p[j]);
        a1[hc] = tmp;
        #pragma unroll
        for (int r = 0; r < 4; ++r)
            bias1[hc][r] = b1p[32 * hs + 16 * hc + 4 * q + r];
    }
    for (int nc = 0; nc < 2; ++nc) {
        const int orow = 16 * nc + bb;                  // W2 row = out idx
        const float* p = w2p + orow * HID + 32 * hs + 8 * q;
        bf16x8 tmp;
        #pragma unroll
        for (int j = 0; j < 8; ++j) tmp[j] = f2bf(p[j]);
        a2[nc] = tmp;
    }

    // ---- update-thread identity: one state element per thread ----
    const int ub = tid >> 5;            // batch row within tile 0..15
    const int ud = tid & 31;            // state dim 0..31
    const float b2d = db2[ud];
    const float b2g = gb2[ud];
    const size_t base = (size_t)(r0 + ub) * DIM + ud;

    float y_reg = y0[base];
    out[base]   = y_reg;                // out[0] = y0
    Ybf[ub * 32 + ud] = f2bf(y_reg);

    // 4-deep noise pipeline (HBM latency ~900 cyc vs ~500 cyc/step)
    float np_[4];
    #pragma unroll
    for (int i = 0; i < 4; ++i) {
        int ti = i; if (ti > T - 1) ti = T - 1;
        np_[i] = noise[(size_t)ti * STEP_E + base];
    }
    LDS_BARRIER();

    const float dt = 0.01f, sdt = 0.1f;
    const f32x4 z = {0.f, 0.f, 0.f, 0.f};

    for (int t = 0; t < T; ++t) {
        // prefetch noise[t+4] (clamped)
        int tn = t + 4; if (tn > T - 1) tn = T - 1;
        const float n_far = noise[(size_t)tn * STEP_E + base];

        // ===== phase A: matrix work =====
        // y fragment doubles as B operand of h^T = W1 * y^T (n=lane&15, k=q*8+j)
        const bf16x8 by = *(const bf16x8*)(&Ybf[bb * 32 + 8 * q]);

        f32x4 hh[2];
        hh[0] = __builtin_amdgcn_mfma_f32_16x16x32_bf16(a1[0], by, z, 0, 0, 0);
        hh[1] = __builtin_amdgcn_mfma_f32_16x16x32_bf16(a1[1], by, z, 0, 0, 0);

        // bias + ReLU + bf16 pack, C-layout -> LDS [batch][hidden_local]
        #pragma unroll
        for (int hc = 0; hc < 2; ++hc) {
            const float v0 = fmaxf(hh[hc][0] + bias1[hc][0], 0.f);
            const float v1 = fmaxf(hh[hc][1] + bias1[hc][1], 0.f);
            const float v2 = fmaxf(hh[hc][2] + bias1[hc][2], 0.f);
            const float v3 = fmaxf(hh[hc][3] + bias1[hc][3], 0.f);
            uint2 dw; dw.x = pack2(v0, v1); dw.y = pack2(v2, v3);
            *(uint2*)(&Hbuf[w][bb * 40 + 16 * hc + 4 * q]) = dw;
        }

        // read back as B operand of f^T = W2 * h^T (k local = q*8+j)
        const bf16x8 hf = *(const bf16x8*)(&Hbuf[w][bb * 40 + 8 * q]);

        const f32x4 p0 = __builtin_amdgcn_mfma_f32_16x16x32_bf16(a2[0], hf, z, 0, 0, 0);
        const f32x4 p1 = __builtin_amdgcn_mfma_f32_16x16x32_bf16(a2[1], hf, z, 0, 0, 0);
        *(f32x4*)(&Fpart[w][bb * 36 + 0  + 4 * q]) = p0;   // out dims 0..15
        *(f32x4*)(&Fpart[w][bb * 36 + 16 + 4 * q]) = p1;   // out dims 16..31
        LDS_BARRIER();

        // ===== phase B: Euler–Maruyama update (1 element / thread) =====
        const int fo = ub * 36 + ud;
        const float fsum = Fpart[0][fo] + Fpart[1][fo] + Fpart[2][fo] + Fpart[3][fo];
        const float gsum = Fpart[4][fo] + Fpart[5][fo] + Fpart[6][fo] + Fpart[7][fo];

        const float y1 = y_reg + (fsum + b2d) * dt + (gsum + b2g) * (sdt * np_[0]);
        y_reg = y1;
        out[(size_t)(t + 1) * STEP_E + base] = y1;   // coalesced, fire-and-forget
        Ybf[ub * 32 + ud] = f2bf(y1);

        np_[0] = np_[1]; np_[1] = np_[2]; np_[2] = np_[3]; np_[3] = n_far;
        LDS_BARRIER();
    }
}

extern "C" void kernel_launch(void* const* d_in, const int* in_sizes, int n_in,
                              void* d_out, int out_size, void* d_ws, size_t ws_size,
                              hipStream_t stream) {
    // inputs: 0 ts, 1 y0, 2 noise, 3..6 drift w1/b1/w2/b2, 7..10 diff w1/b1/w2/b2
    const float* y0    = (const float*)d_in[1];
    const float* noise = (const float*)d_in[2];
    const float* dw1   = (const float*)d_in[3];
    const float* db1   = (const float*)d_in[4];
    const float* dw2   = (const float*)d_in[5];
    const float* db2   = (const float*)d_in[6];
    const float* gw1   = (const float*)d_in[7];
    const float* gb1   = (const float*)d_in[8];
    const float* gw2   = (const float*)d_in[9];
    const float* gb2   = (const float*)d_in[10];
    float* out = (float*)d_out;

    const int T = in_sizes[2] / STEP_E;   // 500

    sde_kernel<<<BATCH / 16, 512, 0, stream>>>(
        y0, noise, dw1, db1, dw2, db2, gw1, gb1, gw2, gb2, out, T);
}